// Round 10
// baseline (254.296 us; speedup 1.0000x reference)
//
#include <hip/hip_runtime.h>
#include <stdint.h>

#define D_DIM 4096
#define N_ROWS 8192

typedef __attribute__((ext_vector_type(8))) short bfrag8;
typedef __attribute__((ext_vector_type(4))) float facc4;
typedef unsigned long long u64;

union ABfrag { uint32_t u[4]; bfrag8 b; };

__device__ __forceinline__ uint32_t pack_bf16x2(float lo, float hi) {
    union { float f; uint32_t u; } a, b;
    a.f = lo; b.f = hi;
    return (b.u & 0xFFFF0000u) | (a.u >> 16);   // truncate-to-bf16
}

// ---------------------------------------------------------------------------
// Kernel 0: A fp32 -> bf16, XOR-swizzled per-K-chunk image (verified).
// ---------------------------------------------------------------------------
__global__ void __launch_bounds__(256)
prep_A(const float* __restrict__ A, uint32_t* __restrict__ A_sw) {
    const int S = blockIdx.x * 256 + threadIdx.x;  // 0..65535
    const int c = S >> 10;
    const int s = S & 1023;
    const int n = s >> 3;
    const int g = (s & 7) ^ (n & 7);
    const float* src = A + (size_t)n * D_DIM + c * 64 + g * 8;
    float4 f0 = *(const float4*)(src);
    float4 f1 = *(const float4*)(src + 4);
    uint4 o;
    o.x = pack_bf16x2(f0.x, f0.y);
    o.y = pack_bf16x2(f0.z, f0.w);
    o.z = pack_bf16x2(f1.x, f1.y);
    o.w = pack_bf16x2(f1.z, f1.w);
    *(uint4*)(A_sw + (size_t)S * 4) = o;
}

// ---------------------------------------------------------------------------
// Kernel 1: GEMM + sign-pack, BARRIER-FREE K-loop (direct-to-register).
// 512 blocks x 256 threads. Block = 16 rows; wave w = K-quarter [w*1024,..).
// Per wave: 16 rows x 128 cols, 16 chunks of 64-K, 16 MFMA/chunk.
//  - a-frags: direct global float4 loads from L, 3-chunk-deep prefetch ring
//    lp[4][4] (fully unrolled loop -> static indices -> registers).
//  - b-frags: direct global 16B loads from the swizzled A_sw image (same
//    address math as the verified ds_read: slot = n*8 + (gl ^ (n&7))).
//  - NO LDS, NO __syncthreads in the K-loop (neither operand is shared:
//    B has zero intra-wave reuse; L rows/K-range are wave-private).
// Epilogue: waves 1..3 dump acc to LDS (R2-verified XOR-swizzle pattern),
// wave 0 reduces, ballots, verified lo^hi fold -> bit-identical keys.
// (Resubmission x4: rounds 6-9 were GPU-acquisition timeouts, kernel unrun.)
// ---------------------------------------------------------------------------
__global__ void __launch_bounds__(256, 2)
gemm_pack_direct(const float* __restrict__ L, const uint32_t* __restrict__ A_sw,
                 u64* __restrict__ folded) {
    __shared__ facc4 red[3 * 512];   // 24 KB, reduction only

    const int tid  = threadIdx.x;    // 0..255
    const int w    = tid >> 6;       // K-quarter 0..3
    const int lane = tid & 63;
    const int row0 = blockIdx.x * 16;
    const int c = lane & 15;         // MFMA row / col-within-tile
    const int q = lane >> 4;         // MFMA k-octet select

    // L: lane (c,q) needs k = q*8..q*8+7 (ks=0) and +32 (ks=1) of each chunk.
    const float* Lrow = L + (size_t)(row0 + c) * D_DIM + w * 1024 + q * 8;
    // B: chunk image base; per-lane column offset c*32 uint32; swizzled slot.
    const uint32_t* gB0 = A_sw + (size_t)(w * 16) * 4096 + c * 32;
    const int sw0 = (q ^ (c & 7)) * 4;        // gl = q     (ks=0), uint32 units
    const int sw1 = ((4 + q) ^ (c & 7)) * 4;  // gl = 4+q   (ks=1)

    facc4 acc[8];
#pragma unroll
    for (int i = 0; i < 8; i++) acc[i] = (facc4){0.f, 0.f, 0.f, 0.f};

    float4 lp[4][4];                 // 3-deep prefetch ring (static indices)
#pragma unroll
    for (int t = 0; t < 3; t++) {
        const float* p = Lrow + t * 64;
        lp[t][0] = *(const float4*)(p);
        lp[t][1] = *(const float4*)(p + 4);
        lp[t][2] = *(const float4*)(p + 32);
        lp[t][3] = *(const float4*)(p + 36);
    }

#pragma unroll
    for (int t = 0; t < 16; t++) {
        // prefetch chunk t+3 (slot (t+3)&3 is dead: held chunk t-1)
        if (t + 3 < 16) {
            const int s = (t + 3) & 3;
            const float* p = Lrow + (t + 3) * 64;
            lp[s][0] = *(const float4*)(p);
            lp[s][1] = *(const float4*)(p + 4);
            lp[s][2] = *(const float4*)(p + 32);
            lp[s][3] = *(const float4*)(p + 36);
        }
        const int s = t & 3;
        const uint32_t* gB = gB0 + t * 4096;

        ABfrag a0, a1;
        a0.u[0] = pack_bf16x2(lp[s][0].x, lp[s][0].y);
        a0.u[1] = pack_bf16x2(lp[s][0].z, lp[s][0].w);
        a0.u[2] = pack_bf16x2(lp[s][1].x, lp[s][1].y);
        a0.u[3] = pack_bf16x2(lp[s][1].z, lp[s][1].w);
        a1.u[0] = pack_bf16x2(lp[s][2].x, lp[s][2].y);
        a1.u[1] = pack_bf16x2(lp[s][2].z, lp[s][2].w);
        a1.u[2] = pack_bf16x2(lp[s][3].x, lp[s][3].y);
        a1.u[3] = pack_bf16x2(lp[s][3].z, lp[s][3].w);

#pragma unroll
        for (int ct = 0; ct < 8; ct++) {
            bfrag8 b0 = *(const bfrag8*)(gB + ct * 512 + sw0);
            acc[ct] = __builtin_amdgcn_mfma_f32_16x16x32_bf16(a0.b, b0, acc[ct], 0, 0, 0);
        }
#pragma unroll
        for (int ct = 0; ct < 8; ct++) {
            bfrag8 b1 = *(const bfrag8*)(gB + ct * 512 + sw1);
            acc[ct] = __builtin_amdgcn_mfma_f32_16x16x32_bf16(a1.b, b1, acc[ct], 0, 0, 0);
        }
    }

    // ---- K-reduction across waves (R2-verified XOR-swizzle slots).
    const int sw = (lane >> 1) & 7;  // XOR on low-3 bits (ct) -> bijective
    if (w > 0) {
        facc4* dst = red + (w - 1) * 512;
#pragma unroll
        for (int ct = 0; ct < 8; ct++)
            dst[(lane * 8 + ct) ^ sw] = acc[ct];
    }
    __syncthreads();
    if (w == 0) {
#pragma unroll
        for (int sidx = 0; sidx < 3; sidx++) {
            const facc4* src = red + sidx * 512;
#pragma unroll
            for (int ct = 0; ct < 8; ct++)
                acc[ct] += src[(lane * 8 + ct) ^ sw];
        }
        // sign -> 128-bit key -> lo^hi fold (verified mapping:
        // acc[ct][r] of lane (q,c) = row 4q+r, col 16ct+c).
        u64 lo = 0, hi = 0;
        const int rq = lane >> 2;    // this lane's target row q (rows = lanes 0..15)
        const int rr = lane & 3;     // this lane's target row r
#pragma unroll
        for (int ct = 0; ct < 8; ct++) {
#pragma unroll
            for (int r = 0; r < 4; r++) {
                u64 m = __ballot(acc[ct][r] > 0.0f);   // all 64 lanes participate
                if (rr == r) {
                    u64 sl = (m >> (16 * rq)) & 0xFFFFull;
                    if (ct < 4) lo |= sl << (16 * ct);
                    else        hi |= sl << (16 * (ct - 4));
                }
            }
        }
        if (lane < 16)
            folded[row0 + lane] = lo ^ hi;
    }
}

// ---------------------------------------------------------------------------
// Kernel 2: ordered duplicate count, LDS-staged keys, load-balanced rows
// (verified, unchanged).
// ---------------------------------------------------------------------------
__global__ void __launch_bounds__(512)
count_rows(const u64* __restrict__ folded, float* __restrict__ out) {
    __shared__ u64 K[N_ROWS];
    const int tid = threadIdx.x;
    for (int i = tid; i < N_ROWS; i += 512) K[i] = folded[i];
    __syncthreads();

    const int g    = blockIdx.x * 8 + (tid >> 6);   // 0..2047
    const int lane = tid & 63;
    int rows[4];
    u64 my[4];
    int cnt[4] = {0, 0, 0, 0};
#pragma unroll
    for (int r = 0; r < 4; r++) {
        rows[r] = g + 2048 * r;
        my[r] = K[rows[r]];
    }
    const int maxrow = rows[3];
    for (int j = lane; j <= maxrow; j += 64) {
        u64 k = K[j];
#pragma unroll
        for (int r = 0; r < 4; r++)
            cnt[r] += (int)((j <= rows[r]) & (k == my[r]));
    }
#pragma unroll
    for (int r = 0; r < 4; r++) {
        int v = cnt[r];
#pragma unroll
        for (int o = 32; o; o >>= 1) v += __shfl_xor(v, o, 64);
        if (lane == 0) out[rows[r]] = rsqrtf((float)v);
    }
}

extern "C" void kernel_launch(void* const* d_in, const int* in_sizes, int n_in,
                              void* d_out, int out_size, void* d_ws, size_t ws_size,
                              hipStream_t stream) {
    const float* latent = (const float*)d_in[0];   // [128,64,4096] fp32
    const float* A      = (const float*)d_in[1];   // [128,4096] fp32
    float* out          = (float*)d_out;           // [8192] fp32

    uint32_t* A_sw = (uint32_t*)d_ws;                               // 1 MB
    u64* folded = (u64*)((char*)d_ws + (1 << 20));                  // 64 KB

    prep_A<<<256, 256, 0, stream>>>(A, A_sw);
    gemm_pack_direct<<<512, 256, 0, stream>>>(latent, A_sw, folded);
    count_rows<<<256, 512, 0, stream>>>(folded, out);
}

// Round 11
// 234.293 us; speedup vs baseline: 1.0854x; 1.0854x over previous
//
#include <hip/hip_runtime.h>
#include <stdint.h>

#define D_DIM 4096
#define N_ROWS 8192

typedef __attribute__((ext_vector_type(8))) short bfrag8;
typedef __attribute__((ext_vector_type(4))) float facc4;
typedef unsigned long long u64;

__device__ __forceinline__ uint32_t pack_bf16x2(float lo, float hi) {
    union { float f; uint32_t u; } a, b;
    a.f = lo; b.f = hi;
    return (b.u & 0xFFFF0000u) | (a.u >> 16);   // truncate-to-bf16
}

// ---------------------------------------------------------------------------
// Kernel 0: A fp32 -> bf16, XOR-swizzled per-K-chunk image (verified).
// ---------------------------------------------------------------------------
__global__ void __launch_bounds__(256)
prep_A(const float* __restrict__ A, uint32_t* __restrict__ A_sw) {
    const int S = blockIdx.x * 256 + threadIdx.x;  // 0..65535
    const int c = S >> 10;
    const int s = S & 1023;
    const int n = s >> 3;
    const int g = (s & 7) ^ (n & 7);
    const float* src = A + (size_t)n * D_DIM + c * 64 + g * 8;
    float4 f0 = *(const float4*)(src);
    float4 f1 = *(const float4*)(src + 4);
    uint4 o;
    o.x = pack_bf16x2(f0.x, f0.y);
    o.y = pack_bf16x2(f0.z, f0.w);
    o.z = pack_bf16x2(f1.x, f1.y);
    o.w = pack_bf16x2(f1.z, f1.w);
    *(uint4*)(A_sw + (size_t)S * 4) = o;
}

// ---------------------------------------------------------------------------
// Kernel 1: split-K GEMM, BM=128 (R0 gemm_split scaled 32->128 rows).
// Grid (S, 64), 256 thr. Block = 128 rows x 128 cols x (4096/S) K.
// Per K-step (64): stage 128x64 L (fp32->bf16, verified stride-72 layout,
// 4 row-groups of the R0 pattern) + 16KB B via global_load_lds (verified
// swizzled image); compute: each of 4 waves = 64 rows x 64 cols =
// 4m x 4ct x 2ks = 32 MFMAs per K-step (4x R0's 8, 16x n4's 2) -- the
// barrier/drain stall amortizes over 4x more compute, and b-frags get
// 4-way m-reuse. fp32 partials to ws (R0-verified layout).
// ---------------------------------------------------------------------------
__global__ void __launch_bounds__(256, 2)
gemm_split128(const float* __restrict__ L, const uint32_t* __restrict__ A_sw,
              float* __restrict__ partials, int kpb) {
    __shared__ ushort Ls[128 * 72];   // 18432 B
    __shared__ uint4  As[1024];       // 16384 B

    const int tid  = threadIdx.x;
    const int wave = tid >> 6;
    const int lane = tid & 63;
    const int split = blockIdx.x;
    const int row0 = blockIdx.y * 128;
    const int c  = lane & 15;
    const int q  = lane >> 4;
    const int wm = wave >> 1;         // 64-row half
    const int wn = wave & 1;          // 64-col half

    const int lrow = tid >> 3;        // 0..31 (row within 32-row group)
    const int lf4  = tid & 7;
    const float* lsrc = L + (size_t)(row0 + lrow) * D_DIM + lf4 * 4;
    ushort* ldst = &Ls[lrow * 72 + lf4 * 4];

    facc4 acc[4][4];
#pragma unroll
    for (int m = 0; m < 4; m++)
#pragma unroll
        for (int ct = 0; ct < 4; ct++) acc[m][ct] = (facc4){0.f, 0.f, 0.f, 0.f};

    const int kc0 = split * kpb * 64;
    const int kc1 = kc0 + kpb * 64;
    for (int kc = kc0; kc < kc1; kc += 64) {
        const uint32_t* gA = A_sw + (size_t)(kc >> 6) * 4096;
#pragma unroll
        for (int i = 0; i < 4; i++) {
            const int slot0 = wave * 256 + i * 64;
            __builtin_amdgcn_global_load_lds(
                (const __attribute__((address_space(1))) uint32_t*)(gA + (slot0 + lane) * 4),
                (__attribute__((address_space(3))) uint32_t*)(&As[slot0]),
                16, 0, 0);
        }
        // L staging: 4 row-groups of 32 (R0-verified pattern per group).
#pragma unroll
        for (int i = 0; i < 4; i++) {
            const float* p = lsrc + (size_t)i * 32 * D_DIM + kc;
            float4 f0 = *(const float4*)(p);
            float4 f1 = *(const float4*)(p + 32);
            *(uint2*)(ldst + i * 32 * 72) =
                make_uint2(pack_bf16x2(f0.x, f0.y), pack_bf16x2(f0.z, f0.w));
            *(uint2*)(ldst + i * 32 * 72 + 32) =
                make_uint2(pack_bf16x2(f1.x, f1.y), pack_bf16x2(f1.z, f1.w));
        }
        __syncthreads();

#pragma unroll
        for (int ks = 0; ks < 2; ks++) {
            bfrag8 a[4];
#pragma unroll
            for (int m = 0; m < 4; m++)
                a[m] = *(const bfrag8*)&Ls[(64 * wm + 16 * m + c) * 72 + ks * 32 + q * 8];
#pragma unroll
            for (int ct = 0; ct < 4; ct++) {
                const int n  = 64 * wn + 16 * ct + c;
                const int gl = ks * 4 + q;
                bfrag8 b = *(const bfrag8*)&As[n * 8 + (gl ^ (n & 7))];
#pragma unroll
                for (int m = 0; m < 4; m++)
                    acc[m][ct] = __builtin_amdgcn_mfma_f32_16x16x32_bf16(a[m], b, acc[m][ct], 0, 0, 0);
            }
        }
        __syncthreads();
    }

    // C/D layout (verified): row = 4q + r within tile, col = c.
    float* P = partials + ((size_t)split * N_ROWS * 128);
    const int cb = 64 * wn + c;
#pragma unroll
    for (int m = 0; m < 4; m++) {
        const int rb = row0 + 64 * wm + 16 * m + 4 * q;
#pragma unroll
        for (int ct = 0; ct < 4; ct++)
#pragma unroll
            for (int r = 0; r < 4; r++)
                P[(size_t)(rb + r) * 128 + cb + 16 * ct] = acc[m][ct][r];
    }
}

// ---------------------------------------------------------------------------
// Kernel 1b: reduce S partials, sign -> 128-bit key -> 64-bit fold
// (R0-verified, unchanged).
// ---------------------------------------------------------------------------
__global__ void __launch_bounds__(256)
reduce_pack(const float* __restrict__ partials, u64* __restrict__ folded, int S) {
    const int row  = blockIdx.x * 4 + (threadIdx.x >> 6);
    const int lane = threadIdx.x & 63;
    float s0 = 0.f, s1 = 0.f;
    for (int s = 0; s < S; s++) {
        const float* P = partials + ((size_t)s * N_ROWS * 128) + (size_t)row * 128;
        s0 += P[lane];
        s1 += P[lane + 64];
    }
    u64 b0 = __ballot(s0 > 0.0f);
    u64 b1 = __ballot(s1 > 0.0f);
    if (lane == 0) folded[row] = b0 ^ b1;
}

// ---------------------------------------------------------------------------
// Kernel 2: ordered duplicate count, LDS-staged keys, load-balanced rows
// (verified, unchanged).
// ---------------------------------------------------------------------------
__global__ void __launch_bounds__(512)
count_rows(const u64* __restrict__ folded, float* __restrict__ out) {
    __shared__ u64 K[N_ROWS];
    const int tid = threadIdx.x;
    for (int i = tid; i < N_ROWS; i += 512) K[i] = folded[i];
    __syncthreads();

    const int g    = blockIdx.x * 8 + (tid >> 6);   // 0..2047
    const int lane = tid & 63;
    int rows[4];
    u64 my[4];
    int cnt[4] = {0, 0, 0, 0};
#pragma unroll
    for (int r = 0; r < 4; r++) {
        rows[r] = g + 2048 * r;
        my[r] = K[rows[r]];
    }
    const int maxrow = rows[3];
    for (int j = lane; j <= maxrow; j += 64) {
        u64 k = K[j];
#pragma unroll
        for (int r = 0; r < 4; r++)
            cnt[r] += (int)((j <= rows[r]) & (k == my[r]));
    }
#pragma unroll
    for (int r = 0; r < 4; r++) {
        int v = cnt[r];
#pragma unroll
        for (int o = 32; o; o >>= 1) v += __shfl_xor(v, o, 64);
        if (lane == 0) out[rows[r]] = rsqrtf((float)v);
    }
}

extern "C" void kernel_launch(void* const* d_in, const int* in_sizes, int n_in,
                              void* d_out, int out_size, void* d_ws, size_t ws_size,
                              hipStream_t stream) {
    const float* latent = (const float*)d_in[0];   // [128,64,4096] fp32
    const float* A      = (const float*)d_in[1];   // [128,4096] fp32
    float* out          = (float*)d_out;           // [8192] fp32

    uint32_t* A_sw = (uint32_t*)d_ws;                                   // 1 MB
    u64* folded = (u64*)((char*)d_ws + (1 << 20));                      // 64 KB
    float* partials = (float*)((char*)d_ws + (1 << 20) + (1 << 16));    // S * 4 MB

    const size_t base = (1 << 20) + (1 << 16);
    const size_t per_split = (size_t)N_ROWS * 128 * sizeof(float);      // 4 MB
    int S = 1;
    if (ws_size >= base + 8 * per_split)      S = 8;
    else if (ws_size >= base + 4 * per_split) S = 4;
    else if (ws_size >= base + 2 * per_split) S = 2;

    prep_A<<<256, 256, 0, stream>>>(A, A_sw);
    gemm_split128<<<dim3(S, 64), 256, 0, stream>>>(latent, A_sw, partials, 64 / S);
    reduce_pack<<<2048, 256, 0, stream>>>(partials, folded, S);
    count_rows<<<256, 512, 0, stream>>>(folded, out);
}